// Round 5
// baseline (105.220 us; speedup 1.0000x reference)
//
#include <hip/hip_runtime.h>

// NaturalCubicSpline: out[q][ch] = a[i][ch] + f*(b[i][ch] + f*(c[i][ch] + f*d[i][ch]))
// i = clip(ceilf(t)-1, 0, 1022) == searchsorted(arange, t, 'left')-1 clamped;
// frac = t - (float)i (exact, knots = arange).
//
// R3 measured 82 us vs ~38 us write floor (fillBuffer calibration: 7.0 TB/s).
// Theory: 256 MB write stream thrashes per-XCD L2 (32 MB through 4 MB), evicting
// the 512 KB coefficient table -> 1 GB of gathers served from L3 (~60 us), not L2.
// Fix: nontemporal out-stores + t-loads (don't pollute L2), unroll x2 for ILP.
// R4: __builtin_nontemporal_store needs a clang vector type, not HIP float4.

typedef float f32x4 __attribute__((ext_vector_type(4)));

__global__ __launch_bounds__(256) void NaturalCubicSpline_kernel(
    const float* __restrict__ t,
    const float* __restrict__ a,
    const float* __restrict__ b,
    const float* __restrict__ c,
    const float* __restrict__ d,
    float* __restrict__ out,
    int n,        // number of queries (2,000,000)
    int maxidx)   // rows - 1 (== 1022)
{
    const int total  = n * 8;                 // 8 lanes per query, 4 floats/lane
    const int stride = gridDim.x * blockDim.x;
    int gid = blockIdx.x * blockDim.x + threadIdx.x;

    // Main loop: two independent query-chunks per thread per iteration.
    for (; gid + stride < total; gid += 2 * stride) {
        const int g0 = gid, g1 = gid + stride;
        const int q0 = g0 >> 3,          q1 = g1 >> 3;
        const int ch0 = (g0 & 7) << 2,   ch1 = (g1 & 7) << 2;

        const float t0 = __builtin_nontemporal_load(t + q0);
        const float t1 = __builtin_nontemporal_load(t + q1);

        int i0 = (int)ceilf(t0) - 1; i0 = i0 < 0 ? 0 : (i0 > maxidx ? maxidx : i0);
        int i1 = (int)ceilf(t1) - 1; i1 = i1 < 0 ? 0 : (i1 > maxidx ? maxidx : i1);
        const float f0 = t0 - (float)i0;
        const float f1 = t1 - (float)i1;

        const int base0 = i0 * 32 + ch0;
        const int base1 = i1 * 32 + ch1;

        const f32x4 a0 = *reinterpret_cast<const f32x4*>(a + base0);
        const f32x4 a1 = *reinterpret_cast<const f32x4*>(a + base1);
        const f32x4 b0 = *reinterpret_cast<const f32x4*>(b + base0);
        const f32x4 b1 = *reinterpret_cast<const f32x4*>(b + base1);
        const f32x4 c0 = *reinterpret_cast<const f32x4*>(c + base0);
        const f32x4 c1 = *reinterpret_cast<const f32x4*>(c + base1);
        const f32x4 d0 = *reinterpret_cast<const f32x4*>(d + base0);
        const f32x4 d1 = *reinterpret_cast<const f32x4*>(d + base1);

        f32x4 r0, r1;
        r0.x = fmaf(fmaf(fmaf(d0.x, f0, c0.x), f0, b0.x), f0, a0.x);
        r0.y = fmaf(fmaf(fmaf(d0.y, f0, c0.y), f0, b0.y), f0, a0.y);
        r0.z = fmaf(fmaf(fmaf(d0.z, f0, c0.z), f0, b0.z), f0, a0.z);
        r0.w = fmaf(fmaf(fmaf(d0.w, f0, c0.w), f0, b0.w), f0, a0.w);
        r1.x = fmaf(fmaf(fmaf(d1.x, f1, c1.x), f1, b1.x), f1, a1.x);
        r1.y = fmaf(fmaf(fmaf(d1.y, f1, c1.y), f1, b1.y), f1, a1.y);
        r1.z = fmaf(fmaf(fmaf(d1.z, f1, c1.z), f1, b1.z), f1, a1.z);
        r1.w = fmaf(fmaf(fmaf(d1.w, f1, c1.w), f1, b1.w), f1, a1.w);

        __builtin_nontemporal_store(r0, reinterpret_cast<f32x4*>(out + q0 * 32 + ch0));
        __builtin_nontemporal_store(r1, reinterpret_cast<f32x4*>(out + q1 * 32 + ch1));
    }

    // Tail: at most one chunk left per thread.
    for (; gid < total; gid += stride) {
        const int q  = gid >> 3;
        const int ch = (gid & 7) << 2;

        const float tv = __builtin_nontemporal_load(t + q);
        int idx = (int)ceilf(tv) - 1;
        idx = idx < 0 ? 0 : (idx > maxidx ? maxidx : idx);
        const float frac = tv - (float)idx;

        const int base = idx * 32 + ch;
        const f32x4 av = *reinterpret_cast<const f32x4*>(a + base);
        const f32x4 bv = *reinterpret_cast<const f32x4*>(b + base);
        const f32x4 cv = *reinterpret_cast<const f32x4*>(c + base);
        const f32x4 dv = *reinterpret_cast<const f32x4*>(d + base);

        f32x4 r;
        r.x = fmaf(fmaf(fmaf(dv.x, frac, cv.x), frac, bv.x), frac, av.x);
        r.y = fmaf(fmaf(fmaf(dv.y, frac, cv.y), frac, bv.y), frac, av.y);
        r.z = fmaf(fmaf(fmaf(dv.z, frac, cv.z), frac, bv.z), frac, av.z);
        r.w = fmaf(fmaf(fmaf(dv.w, frac, cv.w), frac, bv.w), frac, av.w);

        __builtin_nontemporal_store(r, reinterpret_cast<f32x4*>(out + q * 32 + ch));
    }
}

extern "C" void kernel_launch(void* const* d_in, const int* in_sizes, int n_in,
                              void* d_out, int out_size, void* d_ws, size_t ws_size,
                              hipStream_t stream) {
    const float* t = (const float*)d_in[0];
    // d_in[1] = knots (arange, exploited arithmetically; not dereferenced)
    const float* a = (const float*)d_in[2];
    const float* b = (const float*)d_in[3];
    const float* c = (const float*)d_in[4];
    const float* d = (const float*)d_in[5];
    float* out = (float*)d_out;

    const int n    = in_sizes[0];
    const int rows = in_sizes[2] / 32;   // 1023 segments
    const int maxidx = rows - 1;         // 1022

    const long long total_threads = (long long)n * 8;
    int blocks = (int)((total_threads + 255) / 256);
    if (blocks > 2048) blocks = 2048;    // 2048 x 256 = 32 waves/CU, grid-stride rest

    NaturalCubicSpline_kernel<<<blocks, 256, 0, stream>>>(t, a, b, c, d, out, n, maxidx);
}

// Round 6
// 52.294 us; speedup vs baseline: 2.0121x; 2.0121x over previous
//
#include <hip/hip_runtime.h>

// NaturalCubicSpline: out[q][ch] = a[i][ch] + f*(b[i][ch] + f*(c[i][ch] + f*d[i][ch]))
// i = clip(ceilf(t)-1, 0, 1022) == searchsorted(arange, t, 'left')-1 clamped;
// frac = t - (float)i (exact, knots = arange).
//
// R3: 82 us (plain, 8-lane/query grid-stride). R5: nt stores/loads + unroll = 105 us
// (REGRESSION -> nt reverted; it breaks L2 write path).
// R6 theory: gather MLP starvation. Each query needs 8x64B gather lines (16M misses
// total); R3 serializes an HBM t-load (~600-900cy) before each 8-query gather burst,
// so per-CU outstanding misses ~35 << needed. Fix: wave-tile of 64 queries, ONE
// coalesced t-load per wave, __shfl to distribute t, 8 unrolled sub-iters -> up to
// 32 gathers in flight per wave. Stores unchanged (1KB contiguous per wave instr).

typedef float f32x4 __attribute__((ext_vector_type(4)));

__global__ __launch_bounds__(256) void NaturalCubicSpline_kernel(
    const float* __restrict__ t,
    const float* __restrict__ a,
    const float* __restrict__ b,
    const float* __restrict__ c,
    const float* __restrict__ d,
    float* __restrict__ out,
    int n,        // number of queries (2,000,000)
    int maxidx)   // rows - 1 (== 1022)
{
    const int lane  = threadIdx.x & 63;
    const int g     = lane >> 3;          // query-subindex within each 8-query group
    const int chq   = (lane & 7) << 2;    // channel offset: 0,4,...,28

    const int ntiles      = n >> 6;       // 64 queries per wave-tile
    const int waves_total = (gridDim.x * blockDim.x) >> 6;
    int wtile = (blockIdx.x * blockDim.x + threadIdx.x) >> 6;

    for (; wtile < ntiles; wtile += waves_total) {
        const int qbase = wtile << 6;
        // One coalesced 256B load covers all 64 queries' t values for this wave.
        const float tv_all = t[qbase + lane];

#pragma unroll
        for (int s = 0; s < 8; ++s) {
            // lane handles query qbase + s*8 + g, channels chq..chq+3
            const float tq = __shfl(tv_all, s * 8 + g, 64);
            int idx = (int)ceilf(tq) - 1;
            idx = idx < 0 ? 0 : (idx > maxidx ? maxidx : idx);
            const float f = tq - (float)idx;

            const int base = idx * 32 + chq;
            const f32x4 av = *reinterpret_cast<const f32x4*>(a + base);
            const f32x4 bv = *reinterpret_cast<const f32x4*>(b + base);
            const f32x4 cv = *reinterpret_cast<const f32x4*>(c + base);
            const f32x4 dv = *reinterpret_cast<const f32x4*>(d + base);

            f32x4 r;
            r.x = fmaf(fmaf(fmaf(dv.x, f, cv.x), f, bv.x), f, av.x);
            r.y = fmaf(fmaf(fmaf(dv.y, f, cv.y), f, bv.y), f, av.y);
            r.z = fmaf(fmaf(fmaf(dv.z, f, cv.z), f, bv.z), f, av.z);
            r.w = fmaf(fmaf(fmaf(dv.w, f, cv.w), f, bv.w), f, av.w);

            *reinterpret_cast<f32x4*>(out + (qbase + s * 8 + g) * 32 + chq) = r;
        }
    }

    // Tail: queries not covered by full 64-query tiles (n % 64). For n=2M this is 0,
    // but keep it general. Chunk = (query, ch-quad).
    const int tail_start  = ntiles << 6;
    const int tail_chunks = (n - tail_start) * 8;
    if (tail_chunks > 0) {
        const int stride = gridDim.x * blockDim.x;
        for (int k = blockIdx.x * blockDim.x + threadIdx.x; k < tail_chunks; k += stride) {
            const int q  = tail_start + (k >> 3);
            const int ch = (k & 7) << 2;
            const float tv = t[q];
            int idx = (int)ceilf(tv) - 1;
            idx = idx < 0 ? 0 : (idx > maxidx ? maxidx : idx);
            const float f = tv - (float)idx;
            const int base = idx * 32 + ch;
            const f32x4 av = *reinterpret_cast<const f32x4*>(a + base);
            const f32x4 bv = *reinterpret_cast<const f32x4*>(b + base);
            const f32x4 cv = *reinterpret_cast<const f32x4*>(c + base);
            const f32x4 dv = *reinterpret_cast<const f32x4*>(d + base);
            f32x4 r;
            r.x = fmaf(fmaf(fmaf(dv.x, f, cv.x), f, bv.x), f, av.x);
            r.y = fmaf(fmaf(fmaf(dv.y, f, cv.y), f, bv.y), f, av.y);
            r.z = fmaf(fmaf(fmaf(dv.z, f, cv.z), f, bv.z), f, av.z);
            r.w = fmaf(fmaf(fmaf(dv.w, f, cv.w), f, bv.w), f, av.w);
            *reinterpret_cast<f32x4*>(out + q * 32 + ch) = r;
        }
    }
}

extern "C" void kernel_launch(void* const* d_in, const int* in_sizes, int n_in,
                              void* d_out, int out_size, void* d_ws, size_t ws_size,
                              hipStream_t stream) {
    const float* t = (const float*)d_in[0];
    // d_in[1] = knots (arange, exploited arithmetically; not dereferenced)
    const float* a = (const float*)d_in[2];
    const float* b = (const float*)d_in[3];
    const float* c = (const float*)d_in[4];
    const float* d = (const float*)d_in[5];
    float* out = (float*)d_out;

    const int n    = in_sizes[0];
    const int rows = in_sizes[2] / 32;   // 1023 segments
    const int maxidx = rows - 1;         // 1022

    // One 64-query tile per wave: blocks = ceil(ntiles / waves_per_block).
    const int ntiles = n >> 6;
    int blocks = (ntiles + 3) / 4;       // 4 waves per 256-thread block
    if (blocks < 1) blocks = 1;

    NaturalCubicSpline_kernel<<<blocks, 256, 0, stream>>>(t, a, b, c, d, out, n, maxidx);
}

// Round 7
// 52.094 us; speedup vs baseline: 2.0198x; 1.0038x over previous
//
#include <hip/hip_runtime.h>

// NaturalCubicSpline: out[q][ch] = a[i][ch] + f*(b[i][ch] + f*(c[i][ch] + f*d[i][ch]))
// i = clip(ceilf(t)-1, 0, 1022); frac = t - (float)i (exact, knots = arange).
//
// Ladder: R3 plain grid-stride = 82 us. R5 nontemporal = 105 us (REGRESSED, reverted).
// R6 wave-tile (64 q/wave, 1 coalesced t-load + shfl, 8x unroll) = 52.3 us.
// Floor: writes 256MB@7.1TB/s ~= 36-38 us; line transactions 20M @ 1/cyc/CU ~= 33 us.
// R7: close the 52->40 gap: (a) __launch_bounds__(256,3) caps VGPR<=168 so >=3
// waves/SIMD hide gather latency; (b) grid capped at 2048 blocks, each wave does
// ~4 tiles with next-tile t prefetched during current compute (hides t HBM latency).

typedef float f32x4 __attribute__((ext_vector_type(4)));

__global__ __launch_bounds__(256, 3) void NaturalCubicSpline_kernel(
    const float* __restrict__ t,
    const float* __restrict__ a,
    const float* __restrict__ b,
    const float* __restrict__ c,
    const float* __restrict__ d,
    float* __restrict__ out,
    int n,        // number of queries (2,000,000)
    int maxidx)   // rows - 1 (== 1022)
{
    const int lane = threadIdx.x & 63;
    const int g    = lane >> 3;           // query-subindex within each 8-query group
    const int chq  = (lane & 7) << 2;     // channel offset: 0,4,...,28

    const int ntiles      = n >> 6;       // 64 queries per wave-tile
    const int waves_total = (gridDim.x * blockDim.x) >> 6;
    int wtile = (blockIdx.x * blockDim.x + threadIdx.x) >> 6;

    if (wtile < ntiles) {
        float tv = t[(wtile << 6) + lane];          // this tile's 64 t values
        while (true) {
            const int next = wtile + waves_total;
            float tv_next = 0.0f;
            if (next < ntiles)
                tv_next = t[(next << 6) + lane];    // prefetch: hides under compute

            const int qbase = wtile << 6;
#pragma unroll
            for (int s = 0; s < 8; ++s) {
                const float tq = __shfl(tv, s * 8 + g, 64);
                int idx = (int)ceilf(tq) - 1;
                idx = idx < 0 ? 0 : (idx > maxidx ? maxidx : idx);
                const float f = tq - (float)idx;

                const int base = idx * 32 + chq;
                const f32x4 av = *reinterpret_cast<const f32x4*>(a + base);
                const f32x4 bv = *reinterpret_cast<const f32x4*>(b + base);
                const f32x4 cv = *reinterpret_cast<const f32x4*>(c + base);
                const f32x4 dv = *reinterpret_cast<const f32x4*>(d + base);

                f32x4 r;
                r.x = fmaf(fmaf(fmaf(dv.x, f, cv.x), f, bv.x), f, av.x);
                r.y = fmaf(fmaf(fmaf(dv.y, f, cv.y), f, bv.y), f, av.y);
                r.z = fmaf(fmaf(fmaf(dv.z, f, cv.z), f, bv.z), f, av.z);
                r.w = fmaf(fmaf(fmaf(dv.w, f, cv.w), f, bv.w), f, av.w);

                *reinterpret_cast<f32x4*>(out + (qbase + s * 8 + g) * 32 + chq) = r;
            }

            if (next >= ntiles) break;
            tv = tv_next;
            wtile = next;
        }
    }

    // Tail: queries not covered by full 64-query tiles (n % 64; 0 for n=2M).
    const int tail_start  = ntiles << 6;
    const int tail_chunks = (n - tail_start) * 8;
    if (tail_chunks > 0) {
        const int stride = gridDim.x * blockDim.x;
        for (int k = blockIdx.x * blockDim.x + threadIdx.x; k < tail_chunks; k += stride) {
            const int q  = tail_start + (k >> 3);
            const int ch = (k & 7) << 2;
            const float tvq = t[q];
            int idx = (int)ceilf(tvq) - 1;
            idx = idx < 0 ? 0 : (idx > maxidx ? maxidx : idx);
            const float f = tvq - (float)idx;
            const int base = idx * 32 + ch;
            const f32x4 av = *reinterpret_cast<const f32x4*>(a + base);
            const f32x4 bv = *reinterpret_cast<const f32x4*>(b + base);
            const f32x4 cv = *reinterpret_cast<const f32x4*>(c + base);
            const f32x4 dv = *reinterpret_cast<const f32x4*>(d + base);
            f32x4 r;
            r.x = fmaf(fmaf(fmaf(dv.x, f, cv.x), f, bv.x), f, av.x);
            r.y = fmaf(fmaf(fmaf(dv.y, f, cv.y), f, bv.y), f, av.y);
            r.z = fmaf(fmaf(fmaf(dv.z, f, cv.z), f, bv.z), f, av.z);
            r.w = fmaf(fmaf(fmaf(dv.w, f, cv.w), f, bv.w), f, av.w);
            *reinterpret_cast<f32x4*>(out + q * 32 + ch) = r;
        }
    }
}

extern "C" void kernel_launch(void* const* d_in, const int* in_sizes, int n_in,
                              void* d_out, int out_size, void* d_ws, size_t ws_size,
                              hipStream_t stream) {
    const float* t = (const float*)d_in[0];
    // d_in[1] = knots (arange, exploited arithmetically; not dereferenced)
    const float* a = (const float*)d_in[2];
    const float* b = (const float*)d_in[3];
    const float* c = (const float*)d_in[4];
    const float* d = (const float*)d_in[5];
    float* out = (float*)d_out;

    const int n    = in_sizes[0];
    const int rows = in_sizes[2] / 32;   // 1023 segments
    const int maxidx = rows - 1;         // 1022

    // 2048 blocks x 4 waves = 8192 waves; each handles ~ntiles/8192 ~= 4 tiles
    // with t-prefetch across tiles.
    const int ntiles = n >> 6;
    int blocks = (ntiles + 3) / 4;
    if (blocks > 2048) blocks = 2048;
    if (blocks < 1) blocks = 1;

    NaturalCubicSpline_kernel<<<blocks, 256, 0, stream>>>(t, a, b, c, d, out, n, maxidx);
}